// Round 1
// baseline (149.837 us; speedup 1.0000x reference)
//
#include <hip/hip_runtime.h>
#include <hip/hip_bf16.h>

#define L_LAYERS 8
#define S_LEN 2048
#define D_MODEL 128
#define N_TOK (L_LAYERS * S_LEN)
#define FF_DIM 384

typedef __attribute__((ext_vector_type(8))) short bf16x8;
typedef __attribute__((ext_vector_type(4))) float f32x4;
typedef unsigned short u16;
typedef unsigned int u32;

__device__ __forceinline__ u32 bfr(float x) {
  u32 u = __float_as_uint(x);
  return (u + 0x7fffu + ((u >> 16) & 1u)) >> 16;   // RNE f32 -> bf16 bits
}
__device__ __forceinline__ u32 pk2(float lo, float hi) {
  return bfr(lo) | (bfr(hi) << 16);
}

union FragU { u32 u[4]; bf16x8 v; };

__device__ __forceinline__ f32x4 mfma16(bf16x8 a, bf16x8 b, f32x4 c) {
  return __builtin_amdgcn_mfma_f32_16x16x32_bf16(a, b, c, 0, 0, 0);
}

// ---------------------------------------------------------------- weight prep
// qkv_w [128,384] -> qkvT [384][128] bf16 ; out_w [128,128] -> outT [128][128]
// w1 [128,384] -> w1T [384][128] ; w2 [384,128] -> w2T [128][384]
__global__ __launch_bounds__(256) void prep_weights(
    const float* __restrict__ qkv_w, const float* __restrict__ out_w,
    const float* __restrict__ w1, const float* __restrict__ w2,
    u16* __restrict__ qkvT, u16* __restrict__ outT,
    u16* __restrict__ w1T, u16* __restrict__ w2T) {
  int idx = blockIdx.x * 256 + threadIdx.x;
  if (idx < 49152) {                       // qkvT
    int n = idx >> 7, k = idx & 127;
    qkvT[idx] = (u16)bfr(qkv_w[k * 384 + n]);
  } else if (idx < 49152 + 16384) {        // outT
    int i = idx - 49152;
    int n = i >> 7, k = i & 127;
    outT[i] = (u16)bfr(out_w[k * 128 + n]);
  } else if (idx < 49152 + 16384 + 49152) { // w1T
    int i = idx - 49152 - 16384;
    int n = i >> 7, k = i & 127;
    w1T[i] = (u16)bfr(w1[k * 384 + n]);
  } else if (idx < 163840) {               // w2T [128][384]
    int i = idx - 49152 - 16384 - 49152;
    int n = i / 384, k = i - n * 384;
    w2T[i] = (u16)bfr(w2[k * 128 + n]);
  }
}

// ---------------------------------------------------------------- generic GEMM
// C[M=16384, N] = f(A[M,K](f32) * W[K,N]) with WT[N][K] bf16 given.
// 64x64 tile per block, 4 waves in 2x2, BK=128 K-loop, 16x16x32 MFMA.
template <int K, int N, bool BR>
__global__ __launch_bounds__(256) void gemm_bf16(
    const float* __restrict__ A, const u16* __restrict__ WT,
    const float* __restrict__ bias, float* __restrict__ C) {
  __shared__ u16 lds_a[64 * 136];
  __shared__ u16 lds_b[64 * 136];
  const int m0 = blockIdx.x * 64, n0 = blockIdx.y * 64;
  const int tid = threadIdx.x, lane = tid & 63, wv = tid >> 6;
  const int wm = wv >> 1, wn = wv & 1, c = lane & 15, g = lane >> 4;

  f32x4 acc[2][2] = {};
  for (int kt = 0; kt < K / 128; ++kt) {
    if (kt) __syncthreads();
    for (int i = tid; i < 1024; i += 256) {
      int row = i >> 4, c8 = (i & 15) * 8;
      const float4* pa =
          (const float4*)(A + (size_t)(m0 + row) * K + kt * 128 + c8);
      float4 v0 = pa[0], v1 = pa[1];
      uint4 aw = {pk2(v0.x, v0.y), pk2(v0.z, v0.w), pk2(v1.x, v1.y),
                  pk2(v1.z, v1.w)};
      *(uint4*)(&lds_a[row * 136 + c8]) = aw;
      uint4 bw = *(const uint4*)(WT + (size_t)(n0 + row) * K + kt * 128 + c8);
      *(uint4*)(&lds_b[row * 136 + c8]) = bw;
    }
    __syncthreads();
#pragma unroll
    for (int ks = 0; ks < 4; ++ks) {
      bf16x8 a0 = *(bf16x8*)(&lds_a[(wm * 32 + c) * 136 + ks * 32 + 8 * g]);
      bf16x8 a1 = *(bf16x8*)(&lds_a[(wm * 32 + 16 + c) * 136 + ks * 32 + 8 * g]);
      bf16x8 b0 = *(bf16x8*)(&lds_b[(wn * 32 + c) * 136 + ks * 32 + 8 * g]);
      bf16x8 b1 = *(bf16x8*)(&lds_b[(wn * 32 + 16 + c) * 136 + ks * 32 + 8 * g]);
      acc[0][0] = mfma16(a0, b0, acc[0][0]);
      acc[0][1] = mfma16(a0, b1, acc[0][1]);
      acc[1][0] = mfma16(a1, b0, acc[1][0]);
      acc[1][1] = mfma16(a1, b1, acc[1][1]);
    }
  }
#pragma unroll
  for (int mi = 0; mi < 2; ++mi)
#pragma unroll
    for (int ni = 0; ni < 2; ++ni) {
      int n = n0 + wn * 32 + ni * 16 + c;
      float bv = 0.f;
      if constexpr (BR) bv = bias[n];
#pragma unroll
      for (int r = 0; r < 4; ++r) {
        int m = m0 + wm * 32 + mi * 16 + 4 * g + r;
        float v = acc[mi][ni][r] + bv;
        if constexpr (BR) v = fmaxf(v, 0.f);
        C[(size_t)m * N + n] = v;
      }
    }
}

// ---------------------------------------------------------------- attention
// qkv: [16384][384] f32 (q|k|v thirds, head-major inside each third).
// Block: (l,h, 64 q-rows) ; 4 waves x 16 q-rows. Flash with KT=64 dbuf tiles.
__global__ __launch_bounds__(256) void attn_kernel(
    const float* __restrict__ qkv, const int* __restrict__ mask,
    float* __restrict__ ctx) {
  __shared__ u16 lds_k[2][64 * 40];   // [key][d] bf16, row stride 40
  __shared__ u16 lds_vt[2][32 * 72];  // [d][key] bf16, row stride 72
  __shared__ u16 lds_p[4][16 * 40];   // per-wave P [q][key]
  __shared__ float lds_mk[2][64];

  const int bid = blockIdx.x;
  const int qt = bid & 31;
  const int lh = bid >> 5;
  const int l = lh >> 2, h = lh & 3;
  const int tid = threadIdx.x, lane = tid & 63, wv = tid >> 6;
  const int c = lane & 15, g = lane >> 4;
  const int tok0 = l * S_LEN;
  const float scale = 0.17677669529663687f;  // 1/sqrt(32)

  // Q fragment (B operand): col(q)=c, k-dims 8g..8g+7, pre-scaled.
  const int qrow = qt * 64 + wv * 16 + c;
  const float* qp = qkv + (size_t)(tok0 + qrow) * 384 + h * 32 + 8 * g;
  float4 q0 = *(const float4*)qp;
  float4 q1 = *(const float4*)(qp + 4);
  FragU qf;
  qf.u[0] = pk2(q0.x * scale, q0.y * scale);
  qf.u[1] = pk2(q0.z * scale, q0.w * scale);
  qf.u[2] = pk2(q1.x * scale, q1.y * scale);
  qf.u[3] = pk2(q1.z * scale, q1.w * scale);
  const float mq = (float)mask[tok0 + qrow];

  f32x4 acc0 = {0.f, 0.f, 0.f, 0.f}, acc1 = {0.f, 0.f, 0.f, 0.f};
  float m_run = -1e30f, lsum = 0.f;
  const f32x4 zf = {0.f, 0.f, 0.f, 0.f};

  auto stage = [&](int buf, int kt0) {
    int key = tid & 63, dg = tid >> 6;
    const float* kp = qkv + (size_t)(tok0 + kt0 + key) * 384 + 128 + h * 32;
    const float* vp = qkv + (size_t)(tok0 + kt0 + key) * 384 + 256 + h * 32;
#pragma unroll
    for (int it = 0; it < 2; ++it) {
      int j = dg + it * 4;  // float4 chunk 0..7 (covers 32 dims)
      float4 kv = *(const float4*)(kp + j * 4);
      uint2 kw = {pk2(kv.x, kv.y), pk2(kv.z, kv.w)};
      *(uint2*)(&lds_k[buf][key * 40 + j * 4]) = kw;
      float4 vv = *(const float4*)(vp + j * 4);
      lds_vt[buf][(j * 4 + 0) * 72 + key] = (u16)bfr(vv.x);
      lds_vt[buf][(j * 4 + 1) * 72 + key] = (u16)bfr(vv.y);
      lds_vt[buf][(j * 4 + 2) * 72 + key] = (u16)bfr(vv.z);
      lds_vt[buf][(j * 4 + 3) * 72 + key] = (u16)bfr(vv.w);
    }
    if (tid < 64) lds_mk[buf][tid] = (float)mask[tok0 + kt0 + tid];
  };

  stage(0, 0);
  __syncthreads();

  for (int t = 0; t < 32; ++t) {
    int cur = t & 1;
    if (t < 31) stage(cur ^ 1, (t + 1) * 64);
#pragma unroll
    for (int ch = 0; ch < 2; ++ch) {
      int kb = ch * 32;
      bf16x8 a0 = *(bf16x8*)(&lds_k[cur][(kb + c) * 40 + 8 * g]);
      bf16x8 a1 = *(bf16x8*)(&lds_k[cur][(kb + 16 + c) * 40 + 8 * g]);
      f32x4 s0 = mfma16(a0, qf.v, zf);  // S^T: row=key, col=q
      f32x4 s1 = mfma16(a1, qf.v, zf);
      float sv[8];
#pragma unroll
      for (int r = 0; r < 4; ++r) {
        float am0 = mq * lds_mk[cur][kb + 4 * g + r];
        sv[r] = am0 * s0[r] + (am0 - 1.0f) * (-1e9f);
        float am1 = mq * lds_mk[cur][kb + 16 + 4 * g + r];
        sv[4 + r] = am1 * s1[r] + (am1 - 1.0f) * (-1e9f);
      }
      float tmax = sv[0];
#pragma unroll
      for (int r = 1; r < 8; ++r) tmax = fmaxf(tmax, sv[r]);
      tmax = fmaxf(tmax, __shfl_xor(tmax, 16));
      tmax = fmaxf(tmax, __shfl_xor(tmax, 32));
      float mnew = fmaxf(m_run, tmax);
      float corr = __expf(m_run - mnew);
      m_run = mnew;
      lsum *= corr;
      acc0 *= corr;
      acc1 *= corr;
      float p[8], psum = 0.f;
#pragma unroll
      for (int r = 0; r < 8; ++r) {
        p[r] = __expf(sv[r] - mnew);
        psum += p[r];
      }
      lsum += psum;
      uint2 pw0 = {pk2(p[0], p[1]), pk2(p[2], p[3])};
      uint2 pw1 = {pk2(p[4], p[5]), pk2(p[6], p[7])};
      *(uint2*)(&lds_p[wv][c * 40 + 4 * g]) = pw0;       // keys 4g..4g+3
      *(uint2*)(&lds_p[wv][c * 40 + 16 + 4 * g]) = pw1;  // keys 16+4g..
      bf16x8 pb = *(bf16x8*)(&lds_p[wv][c * 40 + 8 * g]);  // B: col=q, k=keys
      bf16x8 v0 = *(bf16x8*)(&lds_vt[cur][c * 72 + kb + 8 * g]);
      bf16x8 v1 = *(bf16x8*)(&lds_vt[cur][(16 + c) * 72 + kb + 8 * g]);
      acc0 = mfma16(v0, pb, acc0);  // ctx^T: row=d(0..15), col=q
      acc1 = mfma16(v1, pb, acc1);  // d 16..31
    }
    __syncthreads();
  }
  float lt = lsum;
  lt += __shfl_xor(lt, 16);
  lt += __shfl_xor(lt, 32);
  float inv = 1.0f / lt;
  float* op = ctx + (size_t)(tok0 + qrow) * 128 + h * 32;
  float4 o0 = {acc0[0] * inv, acc0[1] * inv, acc0[2] * inv, acc0[3] * inv};
  float4 o1 = {acc1[0] * inv, acc1[1] * inv, acc1[2] * inv, acc1[3] * inv};
  *(float4*)(op + 4 * g) = o0;
  *(float4*)(op + 16 + 4 * g) = o1;
}

// ---------------------------------------------------------------- residual+LN
__global__ __launch_bounds__(256) void ln_res(
    const float* __restrict__ a, const float* __restrict__ b,
    const float* __restrict__ gain, const float* __restrict__ bias,
    float* __restrict__ out) {
  int token = blockIdx.x * 4 + (threadIdx.x >> 6);
  int lane = threadIdx.x & 63;
  const float2 av = *(const float2*)(a + (size_t)token * 128 + lane * 2);
  const float2 bv = *(const float2*)(b + (size_t)token * 128 + lane * 2);
  float x0 = av.x + bv.x, x1 = av.y + bv.y;
  float s = x0 + x1, q = x0 * x0 + x1 * x1;
#pragma unroll
  for (int off = 32; off >= 1; off >>= 1) {
    s += __shfl_xor(s, off);
    q += __shfl_xor(q, off);
  }
  float mean = s * (1.0f / 128.0f);
  float var = q * (1.0f / 128.0f) - mean * mean;
  float inv = rsqrtf(var + 1e-5f);
  float2 gv = *(const float2*)(gain + lane * 2);
  float2 bev = *(const float2*)(bias + lane * 2);
  float2 o = {gv.x * (x0 - mean) * inv + bev.x,
              gv.y * (x1 - mean) * inv + bev.y};
  *(float2*)(out + (size_t)token * 128 + lane * 2) = o;
}

// ---------------------------------------------------------------- launch
extern "C" void kernel_launch(void* const* d_in, const int* in_sizes, int n_in,
                              void* d_out, int out_size, void* d_ws,
                              size_t ws_size, hipStream_t stream) {
  (void)in_sizes; (void)n_in; (void)out_size; (void)ws_size;
  const float* x = (const float*)d_in[0];
  const int* mask = (const int*)d_in[1];
  const float* qkv_w = (const float*)d_in[2];
  const float* out_w = (const float*)d_in[3];
  const float* w1 = (const float*)d_in[4];
  const float* b1 = (const float*)d_in[5];
  const float* w2 = (const float*)d_in[6];
  const float* b2 = (const float*)d_in[7];
  const float* g1 = (const float*)d_in[8];
  const float* be1 = (const float*)d_in[9];
  const float* g2 = (const float*)d_in[10];
  const float* be2 = (const float*)d_in[11];
  float* out = (float*)d_out;

  char* ws = (char*)d_ws;
  // Region A (24 MB): qkv -> attn_out -> ff (lifetimes disjoint)
  float* qkv = (float*)ws;              // [16384][384]
  float* attn_out = (float*)ws;         // [16384][128]
  float* ff = (float*)ws;               // [16384][384]
  // Region B (8 MB): ctx -> ff2
  float* ctx = (float*)(ws + 25165824); // [16384][128]
  float* ff2 = ctx;
  float* h = (float*)(ws + 25165824 + 8388608);  // [16384][128]
  u16* qkvT = (u16*)(ws + 25165824 + 2 * 8388608);
  u16* outT = qkvT + 384 * 128;
  u16* w1T = outT + 128 * 128;
  u16* w2T = w1T + 384 * 128;

  prep_weights<<<640, 256, 0, stream>>>(qkv_w, out_w, w1, w2, qkvT, outT, w1T,
                                        w2T);
  gemm_bf16<128, 384, false>
      <<<dim3(256, 6), 256, 0, stream>>>(x, qkvT, nullptr, qkv);
  attn_kernel<<<1024, 256, 0, stream>>>(qkv, mask, ctx);
  gemm_bf16<128, 128, false>
      <<<dim3(256, 2), 256, 0, stream>>>(ctx, outT, nullptr, attn_out);
  ln_res<<<4096, 256, 0, stream>>>(attn_out, x, g1, be1, h);
  gemm_bf16<128, 384, true>
      <<<dim3(256, 6), 256, 0, stream>>>(h, w1T, b1, ff);
  gemm_bf16<384, 128, true>
      <<<dim3(256, 2), 256, 0, stream>>>(ff, w2T, b2, ff2);
  ln_res<<<4096, 256, 0, stream>>>(ff2, h, g2, be2, out);
}

// Round 4
// 114.257 us; speedup vs baseline: 1.3114x; 1.3114x over previous
//
#include <hip/hip_runtime.h>
#include <hip/hip_bf16.h>

typedef __attribute__((ext_vector_type(8))) short bf16x8;
typedef __attribute__((ext_vector_type(4))) float f32x4;
typedef unsigned short u16;
typedef unsigned int u32;

__device__ __forceinline__ u32 bfr(float x) {
  u32 u = __float_as_uint(x);
  return (u + 0x7fffu + ((u >> 16) & 1u)) >> 16;  // RNE f32 -> bf16 bits
}
__device__ __forceinline__ u32 pk2(float lo, float hi) {
  return bfr(lo) | (bfr(hi) << 16);
}
__device__ __forceinline__ u32 cvtpk(float lo, float hi) {
  u32 r;
  asm("v_cvt_pk_bf16_f32 %0, %1, %2" : "=v"(r) : "v"(lo), "v"(hi));
  return r;
}

__device__ __forceinline__ f32x4 mfma16(bf16x8 a, bf16x8 b, f32x4 c) {
  return __builtin_amdgcn_mfma_f32_16x16x32_bf16(a, b, c, 0, 0, 0);
}

// ---------------------------------------------------------------- weight prep
__global__ __launch_bounds__(256) void prep_weights(
    const float* __restrict__ qkv_w, const float* __restrict__ out_w,
    const float* __restrict__ w1, const float* __restrict__ w2,
    u16* __restrict__ qkvT, u16* __restrict__ outT,
    u16* __restrict__ w1T, u16* __restrict__ w2T) {
  int idx = blockIdx.x * 256 + threadIdx.x;
  if (idx < 49152) {
    int n = idx >> 7, k = idx & 127;
    qkvT[idx] = (u16)bfr(qkv_w[k * 384 + n]);
  } else if (idx < 49152 + 16384) {
    int i = idx - 49152;
    int n = i >> 7, k = i & 127;
    outT[i] = (u16)bfr(out_w[k * 128 + n]);
  } else if (idx < 49152 + 16384 + 49152) {
    int i = idx - 49152 - 16384;
    int n = i >> 7, k = i & 127;
    w1T[i] = (u16)bfr(w1[k * 384 + n]);
  } else if (idx < 163840) {
    int i = idx - 49152 - 16384 - 49152;
    int n = i / 384, k = i - n * 384;
    w2T[i] = (u16)bfr(w2[k * 128 + n]);
  }
}

__global__ __launch_bounds__(256) void prep_x(const float* __restrict__ x,
                                              u16* __restrict__ xb) {
  int idx = blockIdx.x * 256 + threadIdx.x;
  const float4* p = (const float4*)(x + (size_t)idx * 8);
  float4 a = p[0], b = p[1];
  uint4 w = {pk2(a.x, a.y), pk2(a.z, a.w), pk2(b.x, b.y), pk2(b.z, b.w)};
  *(uint4*)(xb + (size_t)idx * 8) = w;
}

// ---------------------------------------------------------------- generic GEMM
// C[M=16384,N] = f(A[M,K] bf16 * WT[N][K] bf16). 64x64 tile, 4 waves 2x2.
// EPI: 0 = plain f32 C ; 1 = bias+relu f32 C ; 2 = bias+relu bf16 O0 ;
//      3 = qkv epilogue (O0=Qs scaled, O1=Kb, O2=Vt transposed)
template <int K, int N, int EPI>
__global__ __launch_bounds__(256) void gemm_bf16(
    const u16* __restrict__ A, const u16* __restrict__ WT,
    const float* __restrict__ bias, float* __restrict__ C,
    u16* __restrict__ O0, u16* __restrict__ O1, u16* __restrict__ O2) {
  __shared__ u16 lds_a[64 * 136];
  __shared__ u16 lds_b[64 * 136];
  const int m0 = blockIdx.x * 64, n0 = blockIdx.y * 64;
  const int tid = threadIdx.x, lane = tid & 63, wv = tid >> 6;
  const int wm = wv >> 1, wn = wv & 1, c = lane & 15, g = lane >> 4;

  f32x4 acc[2][2] = {};
  for (int kt = 0; kt < K / 128; ++kt) {
    if (kt) __syncthreads();
    for (int i = tid; i < 1024; i += 256) {
      int row = i >> 4, cc = (i & 15) * 8;
      *(uint4*)(&lds_a[row * 136 + cc]) =
          *(const uint4*)(A + (size_t)(m0 + row) * K + kt * 128 + cc);
      *(uint4*)(&lds_b[row * 136 + cc]) =
          *(const uint4*)(WT + (size_t)(n0 + row) * K + kt * 128 + cc);
    }
    __syncthreads();
#pragma unroll
    for (int ks = 0; ks < 4; ++ks) {
      bf16x8 a0 = *(bf16x8*)(&lds_a[(wm * 32 + c) * 136 + ks * 32 + 8 * g]);
      bf16x8 a1 = *(bf16x8*)(&lds_a[(wm * 32 + 16 + c) * 136 + ks * 32 + 8 * g]);
      bf16x8 b0 = *(bf16x8*)(&lds_b[(wn * 32 + c) * 136 + ks * 32 + 8 * g]);
      bf16x8 b1 = *(bf16x8*)(&lds_b[(wn * 32 + 16 + c) * 136 + ks * 32 + 8 * g]);
      acc[0][0] = mfma16(a0, b0, acc[0][0]);
      acc[0][1] = mfma16(a0, b1, acc[0][1]);
      acc[1][0] = mfma16(a1, b0, acc[1][0]);
      acc[1][1] = mfma16(a1, b1, acc[1][1]);
    }
  }
#pragma unroll
  for (int mi = 0; mi < 2; ++mi)
#pragma unroll
    for (int ni = 0; ni < 2; ++ni) {
      const int n = n0 + wn * 32 + ni * 16 + c;
      const int mb = m0 + wm * 32 + mi * 16 + 4 * g;
      if constexpr (EPI == 0) {
#pragma unroll
        for (int r = 0; r < 4; ++r)
          C[(size_t)(mb + r) * N + n] = acc[mi][ni][r];
      } else if constexpr (EPI == 1) {
        float bv = bias[n];
#pragma unroll
        for (int r = 0; r < 4; ++r)
          C[(size_t)(mb + r) * N + n] = fmaxf(acc[mi][ni][r] + bv, 0.f);
      } else if constexpr (EPI == 2) {
        float bv = bias[n];
#pragma unroll
        for (int r = 0; r < 4; ++r)
          O0[(size_t)(mb + r) * N + n] =
              (u16)bfr(fmaxf(acc[mi][ni][r] + bv, 0.f));
      } else {  // EPI == 3 : qkv
        const int reg = n >> 7, hh = (n >> 5) & 3, d = n & 31;
        const int l = mb >> 11, s = mb & 2047;
        const size_t lh = (size_t)l * 4 + hh;
        if (reg == 0) {
#pragma unroll
          for (int r = 0; r < 4; ++r)
            O0[(lh * 2048 + s + r) * 32 + d] =
                (u16)bfr(acc[mi][ni][r] * 0.17677669529663687f);
        } else if (reg == 1) {
#pragma unroll
          for (int r = 0; r < 4; ++r)
            O1[(lh * 2048 + s + r) * 32 + d] = (u16)bfr(acc[mi][ni][r]);
        } else {
          uint2 w = {pk2(acc[mi][ni][0], acc[mi][ni][1]),
                     pk2(acc[mi][ni][2], acc[mi][ni][3])};
          *(uint2*)(O2 + (lh * 32 + d) * 2048 + s) = w;
        }
      }
    }
}

// ---------------------------------------------------------------- attention
// Block: (l,h, 64 q-rows); 4 waves x 16 q. KT=64 dbuf tiles, single softmax
// pass per tile, defer-max rescale, reg-staged T14 split.
__global__ __launch_bounds__(256) void attn2(
    const u16* __restrict__ Qs, const u16* __restrict__ Kb,
    const u16* __restrict__ Vt, const int* __restrict__ mask,
    u16* __restrict__ ctx) {
  __shared__ u16 lds_k[2][64 * 40];   // [key][d]
  __shared__ u16 lds_vt[2][32 * 72];  // [d][key]
  __shared__ u16 lds_p[4][16 * 72];   // per-wave P [q][key 0..63] stride 72
  __shared__ float lds_mk[2][64];

  const int bid = blockIdx.x;
  const int qt = bid & 31, lh = bid >> 5;
  const int tid = threadIdx.x, lane = tid & 63, wv = tid >> 6;
  const int c = lane & 15, g = lane >> 4;
  const int tok0 = (lh >> 2) * 2048;
  const int h = lh & 3;

  const int qrow = qt * 64 + wv * 16 + c;
  const bf16x8 qf = *(const bf16x8*)(Qs + ((size_t)lh * 2048 + qrow) * 32 + 8 * g);
  const float mq = (float)mask[tok0 + qrow];

  const int kr_ = tid & 63, kc_ = tid >> 6;  // K stage: row, 16B chunk
  const int vr_ = tid >> 3, vc_ = tid & 7;   // V stage: row(d), 16B chunk
  const u16* kbase = Kb + ((size_t)lh * 2048) * 32 + kr_ * 32 + kc_ * 8;
  const u16* vbase = Vt + ((size_t)lh * 32 + vr_) * 2048 + vc_ * 8;

  uint4 krg, vrg;
  float mkv;
  auto issue = [&](int kt0) {
    krg = *(const uint4*)(kbase + (size_t)kt0 * 32);
    vrg = *(const uint4*)(vbase + kt0);
    mkv = (tid < 64) ? (float)mask[tok0 + kt0 + tid] : 0.f;
  };
  auto commit = [&](int buf) {
    *(uint4*)(&lds_k[buf][kr_ * 40 + kc_ * 8]) = krg;
    *(uint4*)(&lds_vt[buf][vr_ * 72 + vc_ * 8]) = vrg;
    if (tid < 64) lds_mk[buf][tid] = mkv;
  };

  issue(0);
  commit(0);
  __syncthreads();

  f32x4 acc0 = {0.f, 0.f, 0.f, 0.f}, acc1 = {0.f, 0.f, 0.f, 0.f};
  float m_run = -1e30f, lsum = 0.f;
  const f32x4 zf = {0.f, 0.f, 0.f, 0.f};

  for (int t = 0; t < 32; ++t) {
    const int cur = t & 1;
    if (t < 31) issue((t + 1) * 64);

    // QK^T -> S^T (row=key via reg, col=q via lane)
    f32x4 s[4];
#pragma unroll
    for (int j = 0; j < 4; ++j) {
      bf16x8 a = *(bf16x8*)(&lds_k[cur][(16 * j + c) * 40 + 8 * g]);
      s[j] = mfma16(a, qf, zf);
    }
    // faithful mask: am*sc + (am-1)*(-1e9)  -- NO algebraic refactor:
    // (sc-1e9)+1e9 quantizes sc to f32-ulp(1e9)=64 (round-3 bug).
    float sv[16];
#pragma unroll
    for (int j = 0; j < 4; ++j) {
      float4 mk4 = *(float4*)(&lds_mk[cur][16 * j + 4 * g]);  // broadcast
      const float* mkp = (const float*)&mk4;
#pragma unroll
      for (int r = 0; r < 4; ++r) {
        float am = mq * mkp[r];
        sv[4 * j + r] = am * s[j][r] + (am - 1.0f) * (-1e9f);
      }
    }
    float tmax = sv[0];
#pragma unroll
    for (int i = 1; i < 16; ++i) tmax = fmaxf(tmax, sv[i]);
    tmax = fmaxf(tmax, __shfl_xor(tmax, 16));
    tmax = fmaxf(tmax, __shfl_xor(tmax, 32));
    if (!__all(tmax <= m_run + 8.0f)) {  // defer-max (T13)
      float mnew = fmaxf(m_run, tmax);
      float corr = __expf(m_run - mnew);
      m_run = mnew;
      lsum *= corr;
      acc0 *= corr;
      acc1 *= corr;
    }
    float p[16], psum = 0.f;
#pragma unroll
    for (int i = 0; i < 16; ++i) {
      p[i] = __expf(sv[i] - m_run);
      psum += p[i];
    }
    lsum += psum;
    // pack P (keys 16j+4g+r) -> per-wave LDS bounce to B-frag layout
#pragma unroll
    for (int j = 0; j < 4; ++j) {
      uint2 w = {cvtpk(p[4 * j], p[4 * j + 1]), cvtpk(p[4 * j + 2], p[4 * j + 3])};
      *(uint2*)(&lds_p[wv][c * 72 + 16 * j + 4 * g]) = w;
    }
    bf16x8 pb0 = *(bf16x8*)(&lds_p[wv][c * 72 + 8 * g]);
    bf16x8 pb1 = *(bf16x8*)(&lds_p[wv][c * 72 + 32 + 8 * g]);
    bf16x8 v00 = *(bf16x8*)(&lds_vt[cur][c * 72 + 8 * g]);
    bf16x8 v01 = *(bf16x8*)(&lds_vt[cur][c * 72 + 32 + 8 * g]);
    bf16x8 v10 = *(bf16x8*)(&lds_vt[cur][(16 + c) * 72 + 8 * g]);
    bf16x8 v11 = *(bf16x8*)(&lds_vt[cur][(16 + c) * 72 + 32 + 8 * g]);
    acc0 = mfma16(v00, pb0, acc0);
    acc0 = mfma16(v01, pb1, acc0);
    acc1 = mfma16(v10, pb0, acc1);
    acc1 = mfma16(v11, pb1, acc1);

    if (t < 31) commit(cur ^ 1);
    __syncthreads();
  }
  float lt = lsum;
  lt += __shfl_xor(lt, 16);
  lt += __shfl_xor(lt, 32);
  float inv = 1.0f / lt;
  u16* op = ctx + (size_t)(tok0 + qrow) * 128 + h * 32;
  uint2 o0 = {cvtpk(acc0[0] * inv, acc0[1] * inv),
              cvtpk(acc0[2] * inv, acc0[3] * inv)};
  uint2 o1 = {cvtpk(acc1[0] * inv, acc1[1] * inv),
              cvtpk(acc1[2] * inv, acc1[3] * inv)};
  *(uint2*)(op + 4 * g) = o0;
  *(uint2*)(op + 16 + 4 * g) = o1;
}

// ---------------------------------------------------------------- residual+LN
template <bool WB>
__global__ __launch_bounds__(256) void ln_res(
    const float* __restrict__ a, const float* __restrict__ b,
    const float* __restrict__ gain, const float* __restrict__ bias,
    float* __restrict__ out, u16* __restrict__ outb) {
  int token = blockIdx.x * 4 + (threadIdx.x >> 6);
  int lane = threadIdx.x & 63;
  const float2 av = *(const float2*)(a + (size_t)token * 128 + lane * 2);
  const float2 bv = *(const float2*)(b + (size_t)token * 128 + lane * 2);
  float x0 = av.x + bv.x, x1 = av.y + bv.y;
  float s = x0 + x1, q = x0 * x0 + x1 * x1;
#pragma unroll
  for (int off = 32; off >= 1; off >>= 1) {
    s += __shfl_xor(s, off);
    q += __shfl_xor(q, off);
  }
  float mean = s * (1.0f / 128.0f);
  float var = q * (1.0f / 128.0f) - mean * mean;
  float inv = rsqrtf(var + 1e-5f);
  float2 gv = *(const float2*)(gain + lane * 2);
  float2 bev = *(const float2*)(bias + lane * 2);
  float2 o = {gv.x * (x0 - mean) * inv + bev.x,
              gv.y * (x1 - mean) * inv + bev.y};
  *(float2*)(out + (size_t)token * 128 + lane * 2) = o;
  if constexpr (WB)
    *(u32*)(outb + (size_t)token * 128 + lane * 2) = pk2(o.x, o.y);
}

// ---------------------------------------------------------------- launch
extern "C" void kernel_launch(void* const* d_in, const int* in_sizes, int n_in,
                              void* d_out, int out_size, void* d_ws,
                              size_t ws_size, hipStream_t stream) {
  (void)in_sizes; (void)n_in; (void)out_size; (void)ws_size;
  const float* x = (const float*)d_in[0];
  const int* mask = (const int*)d_in[1];
  const float* qkv_w = (const float*)d_in[2];
  const float* out_w = (const float*)d_in[3];
  const float* w1 = (const float*)d_in[4];
  const float* b1 = (const float*)d_in[5];
  const float* w2 = (const float*)d_in[6];
  const float* b2 = (const float*)d_in[7];
  const float* g1 = (const float*)d_in[8];
  const float* be1 = (const float*)d_in[9];
  const float* g2 = (const float*)d_in[10];
  const float* be2 = (const float*)d_in[11];
  float* out = (float*)d_out;

  char* ws = (char*)d_ws;
  const size_t MB = 1 << 20;
  // R0 (12MB): Qs|Kb|Vt, later reused as ff_bf
  u16* Qs = (u16*)(ws);
  u16* Kb = (u16*)(ws + 4 * MB);
  u16* Vt = (u16*)(ws + 8 * MB);
  u16* ff_bf = (u16*)(ws);
  u16* ctx_bf = (u16*)(ws + 12 * MB);     // 4MB
  float* attn_out = (float*)(ws + 16 * MB);  // 8MB, later ff2
  float* ff2 = attn_out;
  float* h = (float*)(ws + 24 * MB);      // 8MB
  u16* h_bf = (u16*)(ws + 32 * MB);       // 4MB
  u16* x_bf = (u16*)(ws + 36 * MB);       // 4MB
  u16* qkvT = (u16*)(ws + 40 * MB);
  u16* outT = qkvT + 384 * 128;
  u16* w1T = outT + 128 * 128;
  u16* w2T = w1T + 384 * 128;

  prep_weights<<<640, 256, 0, stream>>>(qkv_w, out_w, w1, w2, qkvT, outT, w1T, w2T);
  prep_x<<<1024, 256, 0, stream>>>(x, x_bf);
  gemm_bf16<128, 384, 3><<<dim3(256, 6), 256, 0, stream>>>(
      x_bf, qkvT, nullptr, nullptr, Qs, Kb, Vt);
  attn2<<<1024, 256, 0, stream>>>(Qs, Kb, Vt, mask, ctx_bf);
  gemm_bf16<128, 128, 0><<<dim3(256, 2), 256, 0, stream>>>(
      ctx_bf, outT, nullptr, attn_out, nullptr, nullptr, nullptr);
  ln_res<true><<<4096, 256, 0, stream>>>(attn_out, x, g1, be1, h, h_bf);
  gemm_bf16<128, 384, 2><<<dim3(256, 6), 256, 0, stream>>>(
      h_bf, w1T, b1, nullptr, ff_bf, nullptr, nullptr);
  gemm_bf16<384, 128, 1><<<dim3(256, 2), 256, 0, stream>>>(
      ff_bf, w2T, b2, ff2, nullptr, nullptr, nullptr);
  ln_res<false><<<4096, 256, 0, stream>>>(ff2, h, g2, be2, out, nullptr);
}

// Round 6
// 110.885 us; speedup vs baseline: 1.3513x; 1.0304x over previous
//
#include <hip/hip_runtime.h>
#include <hip/hip_bf16.h>

typedef __attribute__((ext_vector_type(8))) short bf16x8;
typedef __attribute__((ext_vector_type(4))) float f32x4;
typedef unsigned short u16;
typedef unsigned int u32;

__device__ __forceinline__ u32 bfr(float x) {
  u32 u = __float_as_uint(x);
  return (u + 0x7fffu + ((u >> 16) & 1u)) >> 16;  // RNE f32 -> bf16 bits
}
__device__ __forceinline__ u32 pk2(float lo, float hi) {
  return bfr(lo) | (bfr(hi) << 16);
}
__device__ __forceinline__ u32 cvtpk(float lo, float hi) {
  u32 r;
  asm("v_cvt_pk_bf16_f32 %0, %1, %2" : "=v"(r) : "v"(lo), "v"(hi));
  return r;
}

__device__ __forceinline__ f32x4 mfma16(bf16x8 a, bf16x8 b, f32x4 c) {
  return __builtin_amdgcn_mfma_f32_16x16x32_bf16(a, b, c, 0, 0, 0);
}

// ---------------------------------------------------------------- weight prep
__global__ __launch_bounds__(256) void prep_weights(
    const float* __restrict__ qkv_w, const float* __restrict__ out_w,
    const float* __restrict__ w1, const float* __restrict__ w2,
    u16* __restrict__ qkvT, u16* __restrict__ outT,
    u16* __restrict__ w1T, u16* __restrict__ w2T) {
  int idx = blockIdx.x * 256 + threadIdx.x;
  if (idx < 49152) {
    int n = idx >> 7, k = idx & 127;
    qkvT[idx] = (u16)bfr(qkv_w[k * 384 + n]);
  } else if (idx < 49152 + 16384) {
    int i = idx - 49152;
    int n = i >> 7, k = i & 127;
    outT[i] = (u16)bfr(out_w[k * 128 + n]);
  } else if (idx < 49152 + 16384 + 49152) {
    int i = idx - 49152 - 16384;
    int n = i >> 7, k = i & 127;
    w1T[i] = (u16)bfr(w1[k * 384 + n]);
  } else if (idx < 163840) {
    int i = idx - 49152 - 16384 - 49152;
    int n = i / 384, k = i - n * 384;
    w2T[i] = (u16)bfr(w2[k * 128 + n]);
  }
}

__global__ __launch_bounds__(256) void prep_x(const float* __restrict__ x,
                                              u16* __restrict__ xb) {
  int idx = blockIdx.x * 256 + threadIdx.x;
  const float4* p = (const float4*)(x + (size_t)idx * 8);
  float4 a = p[0], b = p[1];
  uint4 w = {pk2(a.x, a.y), pk2(a.z, a.w), pk2(b.x, b.y), pk2(b.z, b.w)};
  *(uint4*)(xb + (size_t)idx * 8) = w;
}

// ---------------------------------------------------------------- generic GEMM
// C[M=16384,N] = f(A[M,K] bf16 * WT[N][K] bf16). 64x64 tile, 4 waves 2x2.
// EPI: 2 = bias+relu bf16 O0 ; 3 = qkv epilogue (O0=Qs scaled, O1=Kb, O2=Vt)
template <int K, int N, int EPI>
__global__ __launch_bounds__(256) void gemm_bf16(
    const u16* __restrict__ A, const u16* __restrict__ WT,
    const float* __restrict__ bias,
    u16* __restrict__ O0, u16* __restrict__ O1, u16* __restrict__ O2) {
  __shared__ u16 lds_a[64 * 136];
  __shared__ u16 lds_b[64 * 136];
  const int m0 = blockIdx.x * 64, n0 = blockIdx.y * 64;
  const int tid = threadIdx.x, lane = tid & 63, wv = tid >> 6;
  const int wm = wv >> 1, wn = wv & 1, c = lane & 15, g = lane >> 4;

  f32x4 acc[2][2] = {};
  for (int kt = 0; kt < K / 128; ++kt) {
    if (kt) __syncthreads();
    for (int i = tid; i < 1024; i += 256) {
      int row = i >> 4, cc = (i & 15) * 8;
      *(uint4*)(&lds_a[row * 136 + cc]) =
          *(const uint4*)(A + (size_t)(m0 + row) * K + kt * 128 + cc);
      *(uint4*)(&lds_b[row * 136 + cc]) =
          *(const uint4*)(WT + (size_t)(n0 + row) * K + kt * 128 + cc);
    }
    __syncthreads();
#pragma unroll
    for (int ks = 0; ks < 4; ++ks) {
      bf16x8 a0 = *(bf16x8*)(&lds_a[(wm * 32 + c) * 136 + ks * 32 + 8 * g]);
      bf16x8 a1 = *(bf16x8*)(&lds_a[(wm * 32 + 16 + c) * 136 + ks * 32 + 8 * g]);
      bf16x8 b0 = *(bf16x8*)(&lds_b[(wn * 32 + c) * 136 + ks * 32 + 8 * g]);
      bf16x8 b1 = *(bf16x8*)(&lds_b[(wn * 32 + 16 + c) * 136 + ks * 32 + 8 * g]);
      acc[0][0] = mfma16(a0, b0, acc[0][0]);
      acc[0][1] = mfma16(a0, b1, acc[0][1]);
      acc[1][0] = mfma16(a1, b0, acc[1][0]);
      acc[1][1] = mfma16(a1, b1, acc[1][1]);
    }
  }
#pragma unroll
  for (int mi = 0; mi < 2; ++mi)
#pragma unroll
    for (int ni = 0; ni < 2; ++ni) {
      const int n = n0 + wn * 32 + ni * 16 + c;
      const int mb = m0 + wm * 32 + mi * 16 + 4 * g;
      if constexpr (EPI == 2) {
        float bv = bias[n];
#pragma unroll
        for (int r = 0; r < 4; ++r)
          O0[(size_t)(mb + r) * N + n] =
              (u16)bfr(fmaxf(acc[mi][ni][r] + bv, 0.f));
      } else {  // EPI == 3 : qkv
        const int reg = n >> 7, hh = (n >> 5) & 3, d = n & 31;
        const int l = mb >> 11, s = mb & 2047;
        const size_t lh = (size_t)l * 4 + hh;
        if (reg == 0) {
#pragma unroll
          for (int r = 0; r < 4; ++r)
            O0[(lh * 2048 + s + r) * 32 + d] =
                (u16)bfr(acc[mi][ni][r] * 0.17677669529663687f);
        } else if (reg == 1) {
#pragma unroll
          for (int r = 0; r < 4; ++r)
            O1[(lh * 2048 + s + r) * 32 + d] = (u16)bfr(acc[mi][ni][r]);
        } else {
          uint2 w = {pk2(acc[mi][ni][0], acc[mi][ni][1]),
                     pk2(acc[mi][ni][2], acc[mi][ni][3])};
          *(uint2*)(O2 + (lh * 32 + d) * 2048 + s) = w;
        }
      }
    }
}

// ---------------------------------------------- fused GEMM(+bias/relu)+res+LN
// C = A[M,K]*WT[128][K]; t = (RELU ? relu(C+bias) : C) + resid; out = LN(t).
// 64 rows x 128 cols per block, 4 waves x 16 rows.
template <int K, bool RELU>
__global__ __launch_bounds__(256) void gemm_ln(
    const u16* __restrict__ A, const u16* __restrict__ WT,
    const float* __restrict__ bias, const float* __restrict__ resid,
    const float* __restrict__ gain, const float* __restrict__ lnb,
    float* __restrict__ outf, u16* __restrict__ outb) {
  __shared__ u16 lds_a[64 * 136];
  __shared__ u16 lds_b[128 * 136];
  const int m0 = blockIdx.x * 64;
  const int tid = threadIdx.x, lane = tid & 63, wv = tid >> 6;
  const int c = lane & 15, g = lane >> 4;

  f32x4 acc[8] = {};
  for (int kt = 0; kt < K / 128; ++kt) {
    if (kt) __syncthreads();
    for (int i = tid; i < 1024; i += 256) {
      int row = i >> 4, cc = (i & 15) * 8;
      *(uint4*)(&lds_a[row * 136 + cc]) =
          *(const uint4*)(A + (size_t)(m0 + row) * K + kt * 128 + cc);
    }
    for (int i = tid; i < 2048; i += 256) {
      int row = i >> 4, cc = (i & 15) * 8;
      *(uint4*)(&lds_b[row * 136 + cc]) =
          *(const uint4*)(WT + (size_t)row * K + kt * 128 + cc);
    }
    __syncthreads();
#pragma unroll
    for (int ks = 0; ks < 4; ++ks) {
      bf16x8 a = *(bf16x8*)(&lds_a[(wv * 16 + c) * 136 + ks * 32 + 8 * g]);
#pragma unroll
      for (int ni = 0; ni < 8; ++ni) {
        bf16x8 b = *(bf16x8*)(&lds_b[(ni * 16 + c) * 136 + ks * 32 + 8 * g]);
        acc[ni] = mfma16(a, b, acc[ni]);
      }
    }
  }
  // epilogue: rows m0+16wv+4g+r ; lane cols {16ni+c}
  const int rbase = m0 + wv * 16 + 4 * g;
  float gv[8], lb[8], bv[8];
#pragma unroll
  for (int ni = 0; ni < 8; ++ni) {
    gv[ni] = gain[ni * 16 + c];
    lb[ni] = lnb[ni * 16 + c];
    if constexpr (RELU) bv[ni] = bias[ni * 16 + c];
  }
  float t[8][4];
  float sum[4] = {0.f, 0.f, 0.f, 0.f}, sq[4] = {0.f, 0.f, 0.f, 0.f};
#pragma unroll
  for (int ni = 0; ni < 8; ++ni) {
#pragma unroll
    for (int r = 0; r < 4; ++r) {
      float v = acc[ni][r];
      if constexpr (RELU) v = fmaxf(v + bv[ni], 0.f);
      v += resid[(size_t)(rbase + r) * 128 + ni * 16 + c];
      t[ni][r] = v;
      sum[r] += v;
      sq[r] += v * v;
    }
  }
#pragma unroll
  for (int off = 1; off < 16; off <<= 1) {
#pragma unroll
    for (int r = 0; r < 4; ++r) {
      sum[r] += __shfl_xor(sum[r], off);
      sq[r] += __shfl_xor(sq[r], off);
    }
  }
#pragma unroll
  for (int r = 0; r < 4; ++r) {
    float mean = sum[r] * (1.0f / 128.0f);
    float var = sq[r] * (1.0f / 128.0f) - mean * mean;
    float inv = rsqrtf(var + 1e-5f);
#pragma unroll
    for (int ni = 0; ni < 8; ++ni) {
      float o = gv[ni] * (t[ni][r] - mean) * inv + lb[ni];
      outf[(size_t)(rbase + r) * 128 + ni * 16 + c] = o;
      if (outb) outb[(size_t)(rbase + r) * 128 + ni * 16 + c] = (u16)bfr(o);
    }
  }
}

// ---------------------------------------------------------------- attention
// VERBATIM round-4 attn2 (passed absmax 0.031): mask always, f32 lsum,
// cross-lane tmax defer, KT=64 dbuf, per-wave P bounce stride 72.
__global__ __launch_bounds__(256) void attn2(
    const u16* __restrict__ Qs, const u16* __restrict__ Kb,
    const u16* __restrict__ Vt, const int* __restrict__ mask,
    u16* __restrict__ ctx) {
  __shared__ u16 lds_k[2][64 * 40];   // [key][d]
  __shared__ u16 lds_vt[2][32 * 72];  // [d][key]
  __shared__ u16 lds_p[4][16 * 72];   // per-wave P [q][key 0..63] stride 72
  __shared__ float lds_mk[2][64];

  const int bid = blockIdx.x;
  const int qt = bid & 31, lh = bid >> 5;
  const int tid = threadIdx.x, lane = tid & 63, wv = tid >> 6;
  const int c = lane & 15, g = lane >> 4;
  const int tok0 = (lh >> 2) * 2048;
  const int h = lh & 3;

  const int qrow = qt * 64 + wv * 16 + c;
  const bf16x8 qf = *(const bf16x8*)(Qs + ((size_t)lh * 2048 + qrow) * 32 + 8 * g);
  const float mq = (float)mask[tok0 + qrow];

  const int kr_ = tid & 63, kc_ = tid >> 6;  // K stage: row, 16B chunk
  const int vr_ = tid >> 3, vc_ = tid & 7;   // V stage: row(d), 16B chunk
  const u16* kbase = Kb + ((size_t)lh * 2048) * 32 + kr_ * 32 + kc_ * 8;
  const u16* vbase = Vt + ((size_t)lh * 32 + vr_) * 2048 + vc_ * 8;

  uint4 krg, vrg;
  float mkv;
  auto issue = [&](int kt0) {
    krg = *(const uint4*)(kbase + (size_t)kt0 * 32);
    vrg = *(const uint4*)(vbase + kt0);
    mkv = (tid < 64) ? (float)mask[tok0 + kt0 + tid] : 0.f;
  };
  auto commit = [&](int buf) {
    *(uint4*)(&lds_k[buf][kr_ * 40 + kc_ * 8]) = krg;
    *(uint4*)(&lds_vt[buf][vr_ * 72 + vc_ * 8]) = vrg;
    if (tid < 64) lds_mk[buf][tid] = mkv;
  };

  issue(0);
  commit(0);
  __syncthreads();

  f32x4 acc0 = {0.f, 0.f, 0.f, 0.f}, acc1 = {0.f, 0.f, 0.f, 0.f};
  float m_run = -1e30f, lsum = 0.f;
  const f32x4 zf = {0.f, 0.f, 0.f, 0.f};

  for (int t = 0; t < 32; ++t) {
    const int cur = t & 1;
    if (t < 31) issue((t + 1) * 64);

    // QK^T -> S^T (row=key via reg, col=q via lane)
    f32x4 s[4];
#pragma unroll
    for (int j = 0; j < 4; ++j) {
      bf16x8 a = *(bf16x8*)(&lds_k[cur][(16 * j + c) * 40 + 8 * g]);
      s[j] = mfma16(a, qf, zf);
    }
    // faithful mask: am*sc + (am-1)*(-1e9)  -- NO algebraic refactor:
    // (sc-1e9)+1e9 quantizes sc to f32-ulp(1e9)=64 (round-3 bug).
    float sv[16];
#pragma unroll
    for (int j = 0; j < 4; ++j) {
      float4 mk4 = *(float4*)(&lds_mk[cur][16 * j + 4 * g]);  // broadcast
      const float* mkp = (const float*)&mk4;
#pragma unroll
      for (int r = 0; r < 4; ++r) {
        float am = mq * mkp[r];
        sv[4 * j + r] = am * s[j][r] + (am - 1.0f) * (-1e9f);
      }
    }
    float tmax = sv[0];
#pragma unroll
    for (int i = 1; i < 16; ++i) tmax = fmaxf(tmax, sv[i]);
    tmax = fmaxf(tmax, __shfl_xor(tmax, 16));
    tmax = fmaxf(tmax, __shfl_xor(tmax, 32));
    if (!__all(tmax <= m_run + 8.0f)) {  // defer-max (T13)
      float mnew = fmaxf(m_run, tmax);
      float corr = __expf(m_run - mnew);
      m_run = mnew;
      lsum *= corr;
      acc0 *= corr;
      acc1 *= corr;
    }
    float p[16], psum = 0.f;
#pragma unroll
    for (int i = 0; i < 16; ++i) {
      p[i] = __expf(sv[i] - m_run);
      psum += p[i];
    }
    lsum += psum;
    // pack P (keys 16j+4g+r) -> per-wave LDS bounce to B-frag layout
#pragma unroll
    for (int j = 0; j < 4; ++j) {
      uint2 w = {cvtpk(p[4 * j], p[4 * j + 1]), cvtpk(p[4 * j + 2], p[4 * j + 3])};
      *(uint2*)(&lds_p[wv][c * 72 + 16 * j + 4 * g]) = w;
    }
    bf16x8 pb0 = *(bf16x8*)(&lds_p[wv][c * 72 + 8 * g]);
    bf16x8 pb1 = *(bf16x8*)(&lds_p[wv][c * 72 + 32 + 8 * g]);
    bf16x8 v00 = *(bf16x8*)(&lds_vt[cur][c * 72 + 8 * g]);
    bf16x8 v01 = *(bf16x8*)(&lds_vt[cur][c * 72 + 32 + 8 * g]);
    bf16x8 v10 = *(bf16x8*)(&lds_vt[cur][(16 + c) * 72 + 8 * g]);
    bf16x8 v11 = *(bf16x8*)(&lds_vt[cur][(16 + c) * 72 + 32 + 8 * g]);
    acc0 = mfma16(v00, pb0, acc0);
    acc0 = mfma16(v01, pb1, acc0);
    acc1 = mfma16(v10, pb0, acc1);
    acc1 = mfma16(v11, pb1, acc1);

    if (t < 31) commit(cur ^ 1);
    __syncthreads();
  }
  float lt = lsum;
  lt += __shfl_xor(lt, 16);
  lt += __shfl_xor(lt, 32);
  float inv = 1.0f / lt;
  u16* op = ctx + (size_t)(tok0 + qrow) * 128 + h * 32;
  uint2 o0 = {cvtpk(acc0[0] * inv, acc0[1] * inv),
              cvtpk(acc0[2] * inv, acc0[3] * inv)};
  uint2 o1 = {cvtpk(acc1[0] * inv, acc1[1] * inv),
              cvtpk(acc1[2] * inv, acc1[3] * inv)};
  *(uint2*)(op + 4 * g) = o0;
  *(uint2*)(op + 16 + 4 * g) = o1;
}

// ---------------------------------------------------------------- launch
extern "C" void kernel_launch(void* const* d_in, const int* in_sizes, int n_in,
                              void* d_out, int out_size, void* d_ws,
                              size_t ws_size, hipStream_t stream) {
  (void)in_sizes; (void)n_in; (void)out_size; (void)ws_size;
  const float* x = (const float*)d_in[0];
  const int* mask = (const int*)d_in[1];
  const float* qkv_w = (const float*)d_in[2];
  const float* out_w = (const float*)d_in[3];
  const float* w1 = (const float*)d_in[4];
  const float* b1 = (const float*)d_in[5];
  const float* w2 = (const float*)d_in[6];
  const float* b2 = (const float*)d_in[7];
  const float* g1 = (const float*)d_in[8];
  const float* be1 = (const float*)d_in[9];
  const float* g2 = (const float*)d_in[10];
  const float* be2 = (const float*)d_in[11];
  float* out = (float*)d_out;

  char* ws = (char*)d_ws;
  const size_t MB = 1 << 20;
  // [0,12): Qs|Kb|Vt ; after attn reused as ff_bf (12.6MB, spills into dead ctx_bf)
  u16* Qs = (u16*)(ws);
  u16* Kb = (u16*)(ws + 4 * MB);
  u16* Vt = (u16*)(ws + 8 * MB);
  u16* ff_bf = (u16*)(ws);
  u16* ctx_bf = (u16*)(ws + 12 * MB);  // [12,16), dead before ff_bf written
  float* h = (float*)(ws + 16 * MB);   // [16,24)
  u16* h_bf = (u16*)(ws + 24 * MB);    // [24,28)
  u16* x_bf = (u16*)(ws + 28 * MB);    // [28,32)
  u16* qkvT = (u16*)(ws + 32 * MB);
  u16* outT = qkvT + 384 * 128;
  u16* w1T = outT + 128 * 128;
  u16* w2T = w1T + 384 * 128;

  prep_weights<<<640, 256, 0, stream>>>(qkv_w, out_w, w1, w2, qkvT, outT, w1T, w2T);
  prep_x<<<1024, 256, 0, stream>>>(x, x_bf);
  gemm_bf16<128, 384, 3><<<dim3(256, 6), 256, 0, stream>>>(
      x_bf, qkvT, nullptr, Qs, Kb, Vt);
  attn2<<<1024, 256, 0, stream>>>(Qs, Kb, Vt, mask, ctx_bf);
  gemm_ln<128, false><<<256, 256, 0, stream>>>(
      ctx_bf, outT, nullptr, x, g1, be1, h, h_bf);
  gemm_bf16<128, 384, 2><<<dim3(256, 6), 256, 0, stream>>>(
      h_bf, w1T, b1, ff_bf, nullptr, nullptr);
  gemm_ln<384, true><<<256, 256, 0, stream>>>(
      ff_bf, w2T, b2, h, g2, be2, out, nullptr);
}

// Round 7
// 103.910 us; speedup vs baseline: 1.4420x; 1.0671x over previous
//
#include <hip/hip_runtime.h>
#include <hip/hip_bf16.h>

typedef __attribute__((ext_vector_type(8))) short bf16x8;
typedef __attribute__((ext_vector_type(4))) float f32x4;
typedef unsigned short u16;
typedef unsigned int u32;

__device__ __forceinline__ u32 bfr(float x) {
  u32 u = __float_as_uint(x);
  return (u + 0x7fffu + ((u >> 16) & 1u)) >> 16;  // RNE f32 -> bf16 bits
}
__device__ __forceinline__ u32 pk2(float lo, float hi) {
  return bfr(lo) | (bfr(hi) << 16);
}
__device__ __forceinline__ u32 cvtpk(float lo, float hi) {
  u32 r;
  asm("v_cvt_pk_bf16_f32 %0, %1, %2" : "=v"(r) : "v"(lo), "v"(hi));
  return r;
}

__device__ __forceinline__ f32x4 mfma16(bf16x8 a, bf16x8 b, f32x4 c) {
  return __builtin_amdgcn_mfma_f32_16x16x32_bf16(a, b, c, 0, 0, 0);
}

// ---------------------------------------------------------------- weight prep
__global__ __launch_bounds__(256) void prep_weights(
    const float* __restrict__ qkv_w, const float* __restrict__ out_w,
    const float* __restrict__ w1, const float* __restrict__ w2,
    u16* __restrict__ qkvT, u16* __restrict__ outT,
    u16* __restrict__ w1T, u16* __restrict__ w2T) {
  int idx = blockIdx.x * 256 + threadIdx.x;
  if (idx < 49152) {
    int n = idx >> 7, k = idx & 127;
    qkvT[idx] = (u16)bfr(qkv_w[k * 384 + n]);
  } else if (idx < 49152 + 16384) {
    int i = idx - 49152;
    int n = i >> 7, k = i & 127;
    outT[i] = (u16)bfr(out_w[k * 128 + n]);
  } else if (idx < 49152 + 16384 + 49152) {
    int i = idx - 49152 - 16384;
    int n = i >> 7, k = i & 127;
    w1T[i] = (u16)bfr(w1[k * 384 + n]);
  } else if (idx < 163840) {
    int i = idx - 49152 - 16384 - 49152;
    int n = i / 384, k = i - n * 384;
    w2T[i] = (u16)bfr(w2[k * 128 + n]);
  }
}

__global__ __launch_bounds__(256) void prep_x(const float* __restrict__ x,
                                              u16* __restrict__ xb) {
  int idx = blockIdx.x * 256 + threadIdx.x;
  const float4* p = (const float4*)(x + (size_t)idx * 8);
  float4 a = p[0], b = p[1];
  uint4 w = {pk2(a.x, a.y), pk2(a.z, a.w), pk2(b.x, b.y), pk2(b.z, b.w)};
  *(uint4*)(xb + (size_t)idx * 8) = w;
}

// one flag per layer l: 1 iff mask[l, :] is all ones (ballot-based, no
// __syncthreads_and)
__global__ __launch_bounds__(256) void mask_flag(const int* __restrict__ mask,
                                                 int* __restrict__ flag) {
  __shared__ int wbad[4];
  int l = blockIdx.x;
  int bad = 0;
  for (int i = threadIdx.x; i < 2048; i += 256)
    bad |= (mask[l * 2048 + i] != 1);
  unsigned long long b = __ballot(bad != 0);
  if ((threadIdx.x & 63) == 0) wbad[threadIdx.x >> 6] = (b != 0ULL) ? 1 : 0;
  __syncthreads();
  if (threadIdx.x == 0)
    flag[l] = (wbad[0] | wbad[1] | wbad[2] | wbad[3]) ? 0 : 1;
}

// ---------------------------------------------------------------- generic GEMM
// C[M=16384,N] = f(A[M,K] bf16 * WT[N][K] bf16). 64x64 tile, 4 waves 2x2.
// EPI: 2 = bias+relu bf16 O0 ; 3 = qkv epilogue (O0=Qs scaled, O1=Kb, O2=Vt)
template <int K, int N, int EPI>
__global__ __launch_bounds__(256) void gemm_bf16(
    const u16* __restrict__ A, const u16* __restrict__ WT,
    const float* __restrict__ bias,
    u16* __restrict__ O0, u16* __restrict__ O1, u16* __restrict__ O2) {
  __shared__ u16 lds_a[64 * 136];
  __shared__ u16 lds_b[64 * 136];
  const int m0 = blockIdx.x * 64, n0 = blockIdx.y * 64;
  const int tid = threadIdx.x, lane = tid & 63, wv = tid >> 6;
  const int wm = wv >> 1, wn = wv & 1, c = lane & 15, g = lane >> 4;

  f32x4 acc[2][2] = {};
  for (int kt = 0; kt < K / 128; ++kt) {
    if (kt) __syncthreads();
    for (int i = tid; i < 1024; i += 256) {
      int row = i >> 4, cc = (i & 15) * 8;
      *(uint4*)(&lds_a[row * 136 + cc]) =
          *(const uint4*)(A + (size_t)(m0 + row) * K + kt * 128 + cc);
      *(uint4*)(&lds_b[row * 136 + cc]) =
          *(const uint4*)(WT + (size_t)(n0 + row) * K + kt * 128 + cc);
    }
    __syncthreads();
#pragma unroll
    for (int ks = 0; ks < 4; ++ks) {
      bf16x8 a0 = *(bf16x8*)(&lds_a[(wm * 32 + c) * 136 + ks * 32 + 8 * g]);
      bf16x8 a1 = *(bf16x8*)(&lds_a[(wm * 32 + 16 + c) * 136 + ks * 32 + 8 * g]);
      bf16x8 b0 = *(bf16x8*)(&lds_b[(wn * 32 + c) * 136 + ks * 32 + 8 * g]);
      bf16x8 b1 = *(bf16x8*)(&lds_b[(wn * 32 + 16 + c) * 136 + ks * 32 + 8 * g]);
      acc[0][0] = mfma16(a0, b0, acc[0][0]);
      acc[0][1] = mfma16(a0, b1, acc[0][1]);
      acc[1][0] = mfma16(a1, b0, acc[1][0]);
      acc[1][1] = mfma16(a1, b1, acc[1][1]);
    }
  }
#pragma unroll
  for (int mi = 0; mi < 2; ++mi)
#pragma unroll
    for (int ni = 0; ni < 2; ++ni) {
      const int n = n0 + wn * 32 + ni * 16 + c;
      const int mb = m0 + wm * 32 + mi * 16 + 4 * g;
      if constexpr (EPI == 2) {
        float bv = bias[n];
#pragma unroll
        for (int r = 0; r < 4; ++r)
          O0[(size_t)(mb + r) * N + n] =
              (u16)bfr(fmaxf(acc[mi][ni][r] + bv, 0.f));
      } else {  // EPI == 3 : qkv
        const int reg = n >> 7, hh = (n >> 5) & 3, d = n & 31;
        const int l = mb >> 11, s = mb & 2047;
        const size_t lh = (size_t)l * 4 + hh;
        if (reg == 0) {
#pragma unroll
          for (int r = 0; r < 4; ++r)
            O0[(lh * 2048 + s + r) * 32 + d] =
                (u16)bfr(acc[mi][ni][r] * 0.17677669529663687f);
        } else if (reg == 1) {
#pragma unroll
          for (int r = 0; r < 4; ++r)
            O1[(lh * 2048 + s + r) * 32 + d] = (u16)bfr(acc[mi][ni][r]);
        } else {
          uint2 w = {pk2(acc[mi][ni][0], acc[mi][ni][1]),
                     pk2(acc[mi][ni][2], acc[mi][ni][3])};
          *(uint2*)(O2 + (lh * 32 + d) * 2048 + s) = w;
        }
      }
    }
}

// ---------------------------------------------- fused GEMM(+bias/relu)+res+LN
// C = A[M,K]*WT[128][K]; t = (RELU ? relu(C+bias) : C) + resid; out = LN(t).
// 64 rows x 128 cols per block, 4 waves x 16 rows.
template <int K, bool RELU>
__global__ __launch_bounds__(256) void gemm_ln(
    const u16* __restrict__ A, const u16* __restrict__ WT,
    const float* __restrict__ bias, const float* __restrict__ resid,
    const float* __restrict__ gain, const float* __restrict__ lnb,
    float* __restrict__ outf, u16* __restrict__ outb) {
  __shared__ u16 lds_a[64 * 136];
  __shared__ u16 lds_b[128 * 136];
  const int m0 = blockIdx.x * 64;
  const int tid = threadIdx.x, lane = tid & 63, wv = tid >> 6;
  const int c = lane & 15, g = lane >> 4;

  f32x4 acc[8] = {};
  for (int kt = 0; kt < K / 128; ++kt) {
    if (kt) __syncthreads();
    for (int i = tid; i < 1024; i += 256) {
      int row = i >> 4, cc = (i & 15) * 8;
      *(uint4*)(&lds_a[row * 136 + cc]) =
          *(const uint4*)(A + (size_t)(m0 + row) * K + kt * 128 + cc);
    }
    for (int i = tid; i < 2048; i += 256) {
      int row = i >> 4, cc = (i & 15) * 8;
      *(uint4*)(&lds_b[row * 136 + cc]) =
          *(const uint4*)(WT + (size_t)row * K + kt * 128 + cc);
    }
    __syncthreads();
#pragma unroll
    for (int ks = 0; ks < 4; ++ks) {
      bf16x8 a = *(bf16x8*)(&lds_a[(wv * 16 + c) * 136 + ks * 32 + 8 * g]);
#pragma unroll
      for (int ni = 0; ni < 8; ++ni) {
        bf16x8 b = *(bf16x8*)(&lds_b[(ni * 16 + c) * 136 + ks * 32 + 8 * g]);
        acc[ni] = mfma16(a, b, acc[ni]);
      }
    }
  }
  // epilogue: rows m0+16wv+4g+r ; lane cols {16ni+c}
  const int rbase = m0 + wv * 16 + 4 * g;
  float gv[8], lb[8], bv[8];
#pragma unroll
  for (int ni = 0; ni < 8; ++ni) {
    gv[ni] = gain[ni * 16 + c];
    lb[ni] = lnb[ni * 16 + c];
    if constexpr (RELU) bv[ni] = bias[ni * 16 + c];
  }
  float t[8][4];
  float sum[4] = {0.f, 0.f, 0.f, 0.f}, sq[4] = {0.f, 0.f, 0.f, 0.f};
#pragma unroll
  for (int ni = 0; ni < 8; ++ni) {
#pragma unroll
    for (int r = 0; r < 4; ++r) {
      float v = acc[ni][r];
      if constexpr (RELU) v = fmaxf(v + bv[ni], 0.f);
      v += resid[(size_t)(rbase + r) * 128 + ni * 16 + c];
      t[ni][r] = v;
      sum[r] += v;
      sq[r] += v * v;
    }
  }
#pragma unroll
  for (int off = 1; off < 16; off <<= 1) {
#pragma unroll
    for (int r = 0; r < 4; ++r) {
      sum[r] += __shfl_xor(sum[r], off);
      sq[r] += __shfl_xor(sq[r], off);
    }
  }
#pragma unroll
  for (int r = 0; r < 4; ++r) {
    float mean = sum[r] * (1.0f / 128.0f);
    float var = sq[r] * (1.0f / 128.0f) - mean * mean;
    float inv = rsqrtf(var + 1e-5f);
#pragma unroll
    for (int ni = 0; ni < 8; ++ni) {
      float o = gv[ni] * (t[ni][r] - mean) * inv + lb[ni];
      outf[(size_t)(rbase + r) * 128 + ni * 16 + c] = o;
      if (outb) outb[(size_t)(rbase + r) * 128 + ni * 16 + c] = (u16)bfr(o);
    }
  }
}

// ---------------------------------------------------------------- attention
// Round-6 attn2 + ONLY the all-ones-mask fast path (bisection piece A).
__global__ __launch_bounds__(256) void attn4(
    const u16* __restrict__ Qs, const u16* __restrict__ Kb,
    const u16* __restrict__ Vt, const int* __restrict__ mask,
    const int* __restrict__ mflag, u16* __restrict__ ctx) {
  __shared__ u16 lds_k[2][64 * 40];   // [key][d]
  __shared__ u16 lds_vt[2][32 * 72];  // [d][key]
  __shared__ u16 lds_p[4][16 * 72];   // per-wave P [q][key 0..63] stride 72
  __shared__ float lds_mk[2][64];

  const int bid = blockIdx.x;
  const int qt = bid & 31, lh = bid >> 5;
  const int tid = threadIdx.x, lane = tid & 63, wv = tid >> 6;
  const int c = lane & 15, g = lane >> 4;
  const int tok0 = (lh >> 2) * 2048;
  const int h = lh & 3;
  const int allone = mflag[lh >> 2];

  const int qrow = qt * 64 + wv * 16 + c;
  const bf16x8 qf = *(const bf16x8*)(Qs + ((size_t)lh * 2048 + qrow) * 32 + 8 * g);
  const float mq = allone ? 1.0f : (float)mask[tok0 + qrow];

  const int kr_ = tid & 63, kc_ = tid >> 6;  // K stage: row, 16B chunk
  const int vr_ = tid >> 3, vc_ = tid & 7;   // V stage: row(d), 16B chunk
  const u16* kbase = Kb + ((size_t)lh * 2048) * 32 + kr_ * 32 + kc_ * 8;
  const u16* vbase = Vt + ((size_t)lh * 32 + vr_) * 2048 + vc_ * 8;

  uint4 krg, vrg;
  float mkv = 0.f;
  auto issue = [&](int kt0) {
    krg = *(const uint4*)(kbase + (size_t)kt0 * 32);
    vrg = *(const uint4*)(vbase + kt0);
    if (!allone && tid < 64) mkv = (float)mask[tok0 + kt0 + tid];
  };
  auto commit = [&](int buf) {
    *(uint4*)(&lds_k[buf][kr_ * 40 + kc_ * 8]) = krg;
    *(uint4*)(&lds_vt[buf][vr_ * 72 + vc_ * 8]) = vrg;
    if (!allone && tid < 64) lds_mk[buf][tid] = mkv;
  };

  issue(0);
  commit(0);
  __syncthreads();

  f32x4 acc0 = {0.f, 0.f, 0.f, 0.f}, acc1 = {0.f, 0.f, 0.f, 0.f};
  float m_run = -1e30f, lsum = 0.f;
  const f32x4 zf = {0.f, 0.f, 0.f, 0.f};

  for (int t = 0; t < 32; ++t) {
    const int cur = t & 1;
    if (t < 31) issue((t + 1) * 64);

    // QK^T -> S^T (row=key via reg, col=q via lane)
    f32x4 s[4];
#pragma unroll
    for (int j = 0; j < 4; ++j) {
      bf16x8 a = *(bf16x8*)(&lds_k[cur][(16 * j + c) * 40 + 8 * g]);
      s[j] = mfma16(a, qf, zf);
    }
    // faithful mask: am*sc + (am-1)*(-1e9)  -- NO algebraic refactor:
    // (sc-1e9)+1e9 quantizes sc to f32-ulp(1e9)=64 (round-3 bug).
    float sv[16];
    if (allone) {
#pragma unroll
      for (int j = 0; j < 4; ++j)
#pragma unroll
        for (int r = 0; r < 4; ++r) sv[4 * j + r] = s[j][r];
    } else {
#pragma unroll
      for (int j = 0; j < 4; ++j) {
        float4 mk4 = *(float4*)(&lds_mk[cur][16 * j + 4 * g]);  // broadcast
        const float* mkp = (const float*)&mk4;
#pragma unroll
        for (int r = 0; r < 4; ++r) {
          float am = mq * mkp[r];
          sv[4 * j + r] = am * s[j][r] + (am - 1.0f) * (-1e9f);
        }
      }
    }
    float tmax = sv[0];
#pragma unroll
    for (int i = 1; i < 16; ++i) tmax = fmaxf(tmax, sv[i]);
    tmax = fmaxf(tmax, __shfl_xor(tmax, 16));
    tmax = fmaxf(tmax, __shfl_xor(tmax, 32));
    if (!__all(tmax <= m_run + 8.0f)) {  // defer-max (T13)
      float mnew = fmaxf(m_run, tmax);
      float corr = __expf(m_run - mnew);
      m_run = mnew;
      lsum *= corr;
      acc0 *= corr;
      acc1 *= corr;
    }
    float p[16], psum = 0.f;
#pragma unroll
    for (int i = 0; i < 16; ++i) {
      p[i] = __expf(sv[i] - m_run);
      psum += p[i];
    }
    lsum += psum;
    // pack P (keys 16j+4g+r) -> per-wave LDS bounce to B-frag layout
#pragma unroll
    for (int j = 0; j < 4; ++j) {
      uint2 w = {cvtpk(p[4 * j], p[4 * j + 1]), cvtpk(p[4 * j + 2], p[4 * j + 3])};
      *(uint2*)(&lds_p[wv][c * 72 + 16 * j + 4 * g]) = w;
    }
    bf16x8 pb0 = *(bf16x8*)(&lds_p[wv][c * 72 + 8 * g]);
    bf16x8 pb1 = *(bf16x8*)(&lds_p[wv][c * 72 + 32 + 8 * g]);
    bf16x8 v00 = *(bf16x8*)(&lds_vt[cur][c * 72 + 8 * g]);
    bf16x8 v01 = *(bf16x8*)(&lds_vt[cur][c * 72 + 32 + 8 * g]);
    bf16x8 v10 = *(bf16x8*)(&lds_vt[cur][(16 + c) * 72 + 8 * g]);
    bf16x8 v11 = *(bf16x8*)(&lds_vt[cur][(16 + c) * 72 + 32 + 8 * g]);
    acc0 = mfma16(v00, pb0, acc0);
    acc0 = mfma16(v01, pb1, acc0);
    acc1 = mfma16(v10, pb0, acc1);
    acc1 = mfma16(v11, pb1, acc1);

    if (t < 31) commit(cur ^ 1);
    __syncthreads();
  }
  float lt = lsum;
  lt += __shfl_xor(lt, 16);
  lt += __shfl_xor(lt, 32);
  float inv = 1.0f / lt;
  u16* op = ctx + (size_t)(tok0 + qrow) * 128 + h * 32;
  uint2 o0 = {cvtpk(acc0[0] * inv, acc0[1] * inv),
              cvtpk(acc0[2] * inv, acc0[3] * inv)};
  uint2 o1 = {cvtpk(acc1[0] * inv, acc1[1] * inv),
              cvtpk(acc1[2] * inv, acc1[3] * inv)};
  *(uint2*)(op + 4 * g) = o0;
  *(uint2*)(op + 16 + 4 * g) = o1;
}

// ---------------------------------------------------------------- launch
extern "C" void kernel_launch(void* const* d_in, const int* in_sizes, int n_in,
                              void* d_out, int out_size, void* d_ws,
                              size_t ws_size, hipStream_t stream) {
  (void)in_sizes; (void)n_in; (void)out_size; (void)ws_size;
  const float* x = (const float*)d_in[0];
  const int* mask = (const int*)d_in[1];
  const float* qkv_w = (const float*)d_in[2];
  const float* out_w = (const float*)d_in[3];
  const float* w1 = (const float*)d_in[4];
  const float* b1 = (const float*)d_in[5];
  const float* w2 = (const float*)d_in[6];
  const float* b2 = (const float*)d_in[7];
  const float* g1 = (const float*)d_in[8];
  const float* be1 = (const float*)d_in[9];
  const float* g2 = (const float*)d_in[10];
  const float* be2 = (const float*)d_in[11];
  float* out = (float*)d_out;

  char* ws = (char*)d_ws;
  const size_t MB = 1 << 20;
  // [0,12): Qs|Kb|Vt ; after attn reused as ff_bf (12.6MB, spills into dead ctx_bf)
  u16* Qs = (u16*)(ws);
  u16* Kb = (u16*)(ws + 4 * MB);
  u16* Vt = (u16*)(ws + 8 * MB);
  u16* ff_bf = (u16*)(ws);
  u16* ctx_bf = (u16*)(ws + 12 * MB);  // [12,16), dead before ff_bf written
  float* h = (float*)(ws + 16 * MB);   // [16,24)
  u16* h_bf = (u16*)(ws + 24 * MB);    // [24,28)
  u16* x_bf = (u16*)(ws + 28 * MB);    // [28,32)
  u16* qkvT = (u16*)(ws + 32 * MB);
  u16* outT = qkvT + 384 * 128;
  u16* w1T = outT + 128 * 128;
  u16* w2T = w1T + 384 * 128;
  int* mflag = (int*)(ws + 33 * MB);

  prep_weights<<<640, 256, 0, stream>>>(qkv_w, out_w, w1, w2, qkvT, outT, w1T, w2T);
  prep_x<<<1024, 256, 0, stream>>>(x, x_bf);
  mask_flag<<<8, 256, 0, stream>>>(mask, mflag);
  gemm_bf16<128, 384, 3><<<dim3(256, 6), 256, 0, stream>>>(
      x_bf, qkvT, nullptr, Qs, Kb, Vt);
  attn4<<<1024, 256, 0, stream>>>(Qs, Kb, Vt, mask, mflag, ctx_bf);
  gemm_ln<128, false><<<256, 256, 0, stream>>>(
      ctx_bf, outT, nullptr, x, g1, be1, h, h_bf);
  gemm_bf16<128, 384, 2><<<dim3(256, 6), 256, 0, stream>>>(
      h_bf, w1T, b1, ff_bf, nullptr, nullptr);
  gemm_ln<384, true><<<256, 256, 0, stream>>>(
      ff_bf, w2T, b2, h, g2, be2, out, nullptr);
}